// Round 4
// baseline (539.294 us; speedup 1.0000x reference)
//
#include <hip/hip_runtime.h>

// Problem constants: B=16, H=90, LP=512, W=256, L=256, K=384
#define B_     16
#define H_     90
#define LP_    512
#define WL_    65536        // W*L
#define K_     384
#define BHK    (B_ * H_ * K_)   // 552960
#define NCH    64           // csp chunks per batch (mse_stream)
#define CELEM  1024         // elements per chunk

// K1: fused selection — one block per batch, 1024 threads scan the batch's
// 65536 mask ints in 16 coalesced int4 slices. Output: rank16[b][p] = rank
// (0..383) if mask set, else -1. Coalesced short4 writes. One barrier.
// Also zeroes the output scalar.
__global__ __launch_bounds__(1024) void select_kernel(const int* __restrict__ mask,
                                                      short* __restrict__ rank,
                                                      float* __restrict__ out) {
    const int b = blockIdx.x;
    const int t = threadIdx.x;
    if (b == 0 && t == 0) out[0] = 0.0f;
    const int lane = t & 63, wid = t >> 6;

    __shared__ int ws[16][16];          // [slice][wave] inclusive wave totals
    unsigned long long fl = 0ull;       // 4 flag bits per slice
    int wexcl[16];                      // per-slice exclusive rank within wave

    const int4* __restrict__ src = (const int4*)(mask + (size_t)b * WL_);
    #pragma unroll
    for (int i = 0; i < 16; ++i) {
        const int4 v = src[i * 1024 + t];
        const int f0 = v.x != 0, f1 = v.y != 0, f2 = v.z != 0, f3 = v.w != 0;
        fl |= (unsigned long long)(f0 | (f1 << 1) | (f2 << 2) | (f3 << 3)) << (i * 4);
        const int c = f0 + f1 + f2 + f3;
        int incl = c;
        #pragma unroll
        for (int d = 1; d < 64; d <<= 1) {
            const int x = __shfl_up(incl, d, 64);
            if (lane >= d) incl += x;
        }
        if (lane == 63) ws[i][wid] = incl;
        wexcl[i] = incl - c;
    }
    __syncthreads();

    short* __restrict__ rb = rank + (size_t)b * WL_;
    int running = 0;                    // selected count in slices < i
    #pragma unroll
    for (int i = 0; i < 16; ++i) {
        int wbase = 0, tot = 0;
        #pragma unroll
        for (int w = 0; w < 16; ++w) {  // wave-uniform LDS reads -> broadcast
            const int x = ws[i][w];
            tot += x;
            if (w < wid) wbase += x;
        }
        const int f0 = (int)(fl >> (i * 4 + 0)) & 1;
        const int f1 = (int)(fl >> (i * 4 + 1)) & 1;
        const int f2 = (int)(fl >> (i * 4 + 2)) & 1;
        const int f3 = (int)(fl >> (i * 4 + 3)) & 1;
        const int w0 = running + wbase + wexcl[i];
        const int w1 = w0 + f0, w2 = w1 + f1, w3 = w2 + f2;
        running += tot;
        short4 o;
        o.x = f0 ? (short)w0 : (short)-1;
        o.y = f1 ? (short)w1 : (short)-1;
        o.z = f2 ? (short)w2 : (short)-1;
        o.w = f3 ? (short)w3 : (short)-1;
        *(short4*)(rb + i * 4096 + t * 4) = o;
    }
}

// K2: streaming MSE. Replaces the random gather (552,960 divergent 4B
// lane-requests, ~0.37 TB/s effective) with a sequential float4 stream of
// ALL of csp (377 MB, the proven ~6.3 TB/s path). Each block owns one
// (batch, 1024-element chunk); its 4 ranks/thread sit in registers across
// the h-loop; only selected elements (rank >= 0) contribute, with an
// L2-hot divergent cs lookup (~6 lanes per block per h).
// grid = B_*NCH = 1024 blocks x 256 threads -> 16 waves/CU.
__global__ __launch_bounds__(256) void mse_stream(const float* __restrict__ cs,
                                                  const float* __restrict__ csp,
                                                  const short* __restrict__ rank,
                                                  float* __restrict__ out) {
    const int blk = blockIdx.x;
    const int b = blk >> 6;                    // / NCH
    const int c = blk & (NCH - 1);
    const int t = threadIdx.x;
    const int e0 = c * CELEM + t * 4;          // element index within WL_ row

    const short4 r4 = *(const short4*)(rank + (size_t)b * WL_ + e0);
    const float* __restrict__ cspb = csp + ((size_t)b * H_) * WL_ + e0;
    const float* __restrict__ csb  = cs  + ((size_t)b * H_) * LP_;

    float acc0 = 0.0f, acc1 = 0.0f;
    #pragma unroll 2
    for (int h = 0; h < H_; h += 2) {          // 2 rows in flight per thread
        const float4 va = *(const float4*)(cspb + (size_t)h * WL_);
        const float4 vb = *(const float4*)(cspb + (size_t)(h + 1) * WL_);
        const float* __restrict__ ca = csb + h * LP_;
        const float* __restrict__ cb = ca + LP_;
        if (r4.x >= 0) { float d0 = ca[r4.x] - va.x, d1 = cb[r4.x] - vb.x;
                         acc0 = fmaf(d0, d0, acc0); acc1 = fmaf(d1, d1, acc1); }
        if (r4.y >= 0) { float d0 = ca[r4.y] - va.y, d1 = cb[r4.y] - vb.y;
                         acc0 = fmaf(d0, d0, acc0); acc1 = fmaf(d1, d1, acc1); }
        if (r4.z >= 0) { float d0 = ca[r4.z] - va.z, d1 = cb[r4.z] - vb.z;
                         acc0 = fmaf(d0, d0, acc0); acc1 = fmaf(d1, d1, acc1); }
        if (r4.w >= 0) { float d0 = ca[r4.w] - va.w, d1 = cb[r4.w] - vb.w;
                         acc0 = fmaf(d0, d0, acc0); acc1 = fmaf(d1, d1, acc1); }
    }
    float v = acc0 + acc1;
    #pragma unroll
    for (int off = 32; off > 0; off >>= 1) v += __shfl_down(v, off, 64);
    __shared__ float s[4];
    const int lane = t & 63, wid = t >> 6;
    if (lane == 0) s[wid] = v;
    __syncthreads();
    if (t == 0) {
        const float sum = s[0] + s[1] + s[2] + s[3];
        atomicAdd(out, sum * (1.0f / (float)BHK));
    }
}

extern "C" void kernel_launch(void* const* d_in, const int* in_sizes, int n_in,
                              void* d_out, int out_size, void* d_ws, size_t ws_size,
                              hipStream_t stream) {
    const float* cs   = (const float*)d_in[0];   // (B, H, LP) f32
    const float* csp  = (const float*)d_in[1];   // (B, H, W, L) f32
    const int*   mask = (const int*)d_in[2];     // (B, W, L) i32, exactly K ones/batch
    float* out = (float*)d_out;                  // scalar f32

    short* rank = (short*)d_ws;                  // B_*WL_ int16 = 2 MB

    select_kernel<<<B_,        1024, 0, stream>>>(mask, rank, out);
    mse_stream   <<<B_ * NCH,   256, 0, stream>>>(cs, csp, rank, out);
}

// Round 6
// 431.506 us; speedup vs baseline: 1.2498x; 1.2498x over previous
//
#include <hip/hip_runtime.h>

// Problem constants: B=16, H=90, LP=512, W=256, L=256, K=384
#define B_     16
#define H_     90
#define LP_    512
#define WL_    65536        // W*L
#define K_     384
#define BHK    (B_ * H_ * K_)   // 552960
#define CHUNK  1024         // mask ints per block in count/scatter
#define NCHUNK (WL_ / CHUNK)    // 64 chunks per batch
#define NBLK   (B_ * NCHUNK)    // 1024 blocks
#define HG     3            // h-rows per mse block
#define NH     (H_ / HG)    // 30 h-groups

// K1: per-chunk popcount of mask; also zero the output scalar.
// grid = NBLK blocks x 256 threads; each thread loads int4 (16B) -> 4 KB/block.
__global__ __launch_bounds__(256) void count_kernel(const int* __restrict__ mask,
                                                    int* __restrict__ cnt,
                                                    float* __restrict__ out) {
    if (blockIdx.x == 0 && threadIdx.x == 0) out[0] = 0.0f;
    const int4 v = ((const int4*)(mask + (size_t)blockIdx.x * CHUNK))[threadIdx.x];
    int c = (v.x != 0) + (v.y != 0) + (v.z != 0) + (v.w != 0);
    #pragma unroll
    for (int off = 32; off > 0; off >>= 1) c += __shfl_down(c, off, 64);
    __shared__ int s[4];
    const int lane = threadIdx.x & 63, wid = threadIdx.x >> 6;
    if (lane == 0) s[wid] = c;
    __syncthreads();
    if (threadIdx.x == 0) cnt[blockIdx.x] = s[0] + s[1] + s[2] + s[3];
}

// K2: scatter with INLINE segmented scan (replaces the old 1-block scan
// dispatch — pure launch/serialization bubble). Wave 0 additionally scans
// the batch's 64 chunk counts (L2-hot, 64 ints) via shfl to get this
// chunk's base rank; the rest is the stable block-wide compaction.
// grid = NBLK blocks x 256 threads.
__global__ __launch_bounds__(256) void scatter_kernel(const int* __restrict__ mask,
                                                      const int* __restrict__ cnt,
                                                      int* __restrict__ pos) {
    const int blk = blockIdx.x;
    const int b = blk >> 6;                       // blk / NCHUNK
    const int j = blk & (NCHUNK - 1);             // chunk index within batch
    const int t = threadIdx.x;
    const int4 v = ((const int4*)(mask + (size_t)blk * CHUNK))[t];
    const int f0 = v.x != 0, f1 = v.y != 0, f2 = v.z != 0, f3 = v.w != 0;
    const int c = f0 + f1 + f2 + f3;
    const int lane = t & 63, wid = t >> 6;

    __shared__ int ws[4];
    __shared__ int sOff;

    // block-wide exclusive scan of per-thread counts (4 waves)
    int incl = c;
    #pragma unroll
    for (int d = 1; d < 64; d <<= 1) {
        const int x = __shfl_up(incl, d, 64);
        if (lane >= d) incl += x;
    }
    if (lane == 63) ws[wid] = incl;

    // wave 0: exclusive prefix of chunk counts within this batch
    if (wid == 0) {
        const int cc = cnt[(b << 6) + lane];      // 64 ints, L2-hot
        int ci = cc;
        #pragma unroll
        for (int d = 1; d < 64; d <<= 1) {
            const int x = __shfl_up(ci, d, 64);
            if (lane >= d) ci += x;
        }
        if (lane == j) sOff = ci - cc;            // base rank of this chunk
    }
    __syncthreads();

    int wbase = 0;
    #pragma unroll
    for (int wi = 0; wi < 4; ++wi) if (wi < wid) wbase += ws[wi];
    const int excl = wbase + incl - c;

    const int gbase = j * CHUNK + t * 4;          // index within batch's WL_ row
    int w = sOff + excl;                          // rank within batch, 0..K_-1
    int* __restrict__ p = pos + b * K_;
    if (f0) p[w++] = gbase + 0;
    if (f1) p[w++] = gbase + 1;
    if (f2) p[w++] = gbase + 2;
    if (f3) p[w]   = gbase + 3;
}

// K3: MSE gather. One block per (b, group of HG=3 h-rows), 384 threads
// (= K_), thread k handles col k of 3 rows: pos load amortized 3x, 3
// independent gathers in flight. pos is sorted ascending -> monotonic
// wave gather, good DRAM locality (measured ~15 us, NOT the bottleneck).
__global__ __launch_bounds__(384) void mse_kernel(const float* __restrict__ cs,
                                                  const float* __restrict__ csp,
                                                  const int* __restrict__ pos,
                                                  float* __restrict__ out) {
    const int g  = blockIdx.x;                 // 0..B_*NH-1 = 480
    const int b  = g / NH;
    const int h0 = (g - b * NH) * HG;
    const int k  = threadIdx.x;                // 0..383 (< LP_, non-NaN cols)
    const int p  = pos[b * K_ + k];            // L2-hot, shared across h
    const size_t r0 = (size_t)(b * H_ + h0);
    float acc = 0.0f;
    #pragma unroll
    for (int jj = 0; jj < HG; ++jj) {
        const float a = cs [(r0 + jj) * LP_ + k];
        const float c = csp[(r0 + jj) * WL_ + p];
        const float d = a - c;
        acc = fmaf(d, d, acc);
    }
    #pragma unroll
    for (int off = 32; off > 0; off >>= 1) acc += __shfl_down(acc, off, 64);
    __shared__ float s[6];
    const int lane = k & 63, wid = k >> 6;
    if (lane == 0) s[wid] = acc;
    __syncthreads();
    if (k == 0) {
        const float sum = s[0] + s[1] + s[2] + s[3] + s[4] + s[5];
        atomicAdd(out, sum * (1.0f / (float)BHK));
    }
}

extern "C" void kernel_launch(void* const* d_in, const int* in_sizes, int n_in,
                              void* d_out, int out_size, void* d_ws, size_t ws_size,
                              hipStream_t stream) {
    const float* cs   = (const float*)d_in[0];   // (B, H, LP) f32
    const float* csp  = (const float*)d_in[1];   // (B, H, W, L) f32
    const int*   mask = (const int*)d_in[2];     // (B, W, L) i32, exactly K ones/batch
    float* out = (float*)d_out;                  // scalar f32

    // workspace layout
    int* pos = (int*)d_ws;                       // B_*K_ = 6144 ints
    int* cnt = pos + B_ * K_;                    // NBLK   = 1024 ints

    count_kernel  <<<NBLK,    256, 0, stream>>>(mask, cnt, out);
    scatter_kernel<<<NBLK,    256, 0, stream>>>(mask, cnt, pos);
    mse_kernel    <<<B_ * NH, 384, 0, stream>>>(cs, csp, pos, out);
}